// Round 7
// baseline (518.486 us; speedup 1.0000x reference)
//
#include <hip/hip_runtime.h>
#include <stdint.h>

#define E_N 16
#define HID 2048
#define INTER_D 4096
#define NPAIR 2048
#define NTOK 1024
#define CAP 256

typedef __attribute__((ext_vector_type(8))) short bf16x8;
typedef __attribute__((ext_vector_type(4))) float f32x4;

static __device__ __forceinline__ unsigned short f2bf(float f) {
  union { float f; unsigned int u; } x; x.f = f;
  unsigned int r = x.u + 0x7fffu + ((x.u >> 16) & 1u);
  return (unsigned short)(r >> 16);
}

// ---------------- routing: per-expert pair lists ----------------
__global__ void route_kernel(const int* __restrict__ idx, int* __restrict__ counts,
                             int* __restrict__ gidlist) {
  __shared__ int cnt[E_N];
  const int tid = threadIdx.x;
  if (tid < E_N) cnt[tid] = 0;
  for (int j = tid; j < E_N * CAP; j += 256) gidlist[j] = 0;  // pad with valid gid 0
  __syncthreads();
  for (int p = tid; p < NPAIR; p += 256) {
    int e = idx[p] & 15;
    int pos = atomicAdd(&cnt[e], 1);
    if (pos < CAP) gidlist[e * CAP + pos] = p;
  }
  __syncthreads();
  if (tid < E_N) counts[tid] = (cnt[tid] < CAP) ? cnt[tid] : CAP;
}

// ---------------- tokens fp32 -> bf16 ----------------
__global__ void prep_a_kernel(const float* __restrict__ tok, unsigned short* __restrict__ A1) {
  const int i = (blockIdx.x * 256 + threadIdx.x) * 4;
  const float4 v = *reinterpret_cast<const float4*>(tok + i);
  ushort4 o;
  o.x = f2bf(v.x); o.y = f2bf(v.y); o.z = f2bf(v.z); o.w = f2bf(v.w);
  *reinterpret_cast<ushort4*>(A1 + i) = o;
}

// ---------------- grouped GEMM: BM=256 x BN=256, BK=64, 16 waves (4Mx4N, 64x64/wave)
// MODE 0: h = bf16(relu(A1 @ w1 + b1))           KDT=2048, NDIM=4096, KSPLIT=1
// MODE 1: out += tw * (h @ w2 [+ b2 if kh==0])   KDT=4096, NDIM=2048, KSPLIT=2
// 256 blocks each (1/CU, 1 generation). Single barrier/step; A dbuf + B dbuf (128 KiB).
// B staging: 2-way bank-conflict write map + swz(n)=(n^n>>2^n>>4)&7; live B regs = 8.
// Per-tile vmem/wave = 6 {bhA:2, bhB:2, A:2}; counted vmcnt(4), never drained mid-loop.
template <int KDT, int NDIM, int MODE, int KSPLIT>
__global__ __launch_bounds__(1024, 4) void moe_gemm_kernel(
    const unsigned short* __restrict__ Asrc,  // bf16 rows, stride KDT
    const float* __restrict__ W,              // [E][KDT][NDIM] fp32
    const float* __restrict__ bias,           // [E][NDIM]
    const float* __restrict__ tw,             // [NPAIR] (MODE 1)
    const int* __restrict__ counts,
    const int* __restrict__ gidlist,
    unsigned short* __restrict__ Hout,        // MODE 0
    float* __restrict__ Oout) {               // MODE 1 (atomic)
  constexpr int KLOC = KDT / KSPLIT;          // 2048
  constexpr int NK = KLOC / 64;               // 32
  constexpr int NB = NDIM / 256;
  const int bid = blockIdx.x;
  const int e   = bid / (NB * KSPLIT);
  const int rem = bid % (NB * KSPLIT);
  const int nc  = rem / KSPLIT;
  const int kh  = rem % KSPLIT;
  const int ne = counts[e];
  if (ne <= 0) return;
  const int n0 = nc * 256;
  const int tid = threadIdx.x;
  const int lane = tid & 63;
  const int wv = tid >> 6;   // 0..15
  const int wm = wv >> 2;    // M group of 64 rows
  const int wn = wv & 3;     // N group of 64 cols

  extern __shared__ char smem[];
  char* Ab0 = smem;              // 2 x 32 KiB A (bf16 [256][64], source-swizzled)
  char* Ab1 = smem + 32768;
  char* Bs0 = smem + 65536;      // 2 x 32 KiB B (bf16 [256 n][64 k], swz units)
  char* Bs1 = smem + 98304;

  // ---- A staging (global_load_lds; dest linear, source pre-swizzled) ----
  const int c16 = (lane & 7) ^ ((lane >> 3) & 7);
  const int glist0 = e * CAP;
  const unsigned short* arp[2];
#pragma unroll
  for (int i = 0; i < 2; ++i) {
    const int row = (wv * 2 + i) * 8 + (lane >> 3);
    const int gid = gidlist[glist0 + row];
    const long arow = (MODE == 0) ? (gid >> 1) : gid;
    arp[i] = Asrc + arow * (long)KDT + kh * KLOC + c16 * 8;
  }
  auto stageA = [&](int t, char* buf) {
#pragma unroll
    for (int i = 0; i < 2; ++i) {
      char* dst = buf + (wv * 2 + i) * 1024;
      __builtin_amdgcn_global_load_lds(
          (const __attribute__((address_space(1))) void*)(arp[i] + t * 64),
          (__attribute__((address_space(3))) void*)dst, 16, 0, 0);
    }
  };

  // ---- B staging: thread = 2 k-rows x 8 n-cols (two 4-col halves) ----
  const int m16 = lane & 15;
  const int d4  = lane >> 4;                  // k-dword slot
  const int nbase = m16 * 16 + (wv >> 3) * 8;
  const int k0 = (wv & 7) * 8 + d4 * 2;       // even local k row
  const float* wbase = W + ((long)e * KDT + (long)kh * KLOC) * NDIM + n0 + nbase;
  int bby[2][4];
#pragma unroll
  for (int h = 0; h < 2; ++h)
#pragma unroll
    for (int j = 0; j < 4; ++j) {
      const int n = nbase + 4 * h + j;
      const int swz = (n ^ (n >> 2) ^ (n >> 4)) & 7;
      bby[h][j] = n * 128 + (((wv & 7) ^ swz) << 4) + d4 * 4;
    }
  auto loadH = [&](int t, int h, f32x4& r0, f32x4& r1) {
    const float* p = wbase + (long)(t * 64 + k0) * NDIM + 4 * h;
    r0 = *reinterpret_cast<const f32x4*>(p);
    r1 = *reinterpret_cast<const f32x4*>(p + NDIM);
  };
  auto writeH = [&](char* Bb, int h, const f32x4& r0, const f32x4& r1) {
#pragma unroll
    for (int j = 0; j < 4; ++j) {
      unsigned int u = (unsigned int)f2bf(r0[j]) | ((unsigned int)f2bf(r1[j]) << 16);
      *reinterpret_cast<unsigned int*>(Bb + bby[h][j]) = u;
    }
  };

  // ---- fragment LDS byte offsets ----
  const int rl = lane & 15;
  const int kg = lane >> 4;  // 0..3
  int abyte[2], bbF[4][2];
#pragma unroll
  for (int ks = 0; ks < 2; ++ks) {
    const int unit = (ks * 4 + kg) ^ (rl & 7);
    abyte[ks] = (wm * 64 + rl) * 128 + unit * 16;  // + mf*2048 at use
  }
#pragma unroll
  for (int nf = 0; nf < 4; ++nf) {
    const int n = wn * 64 + nf * 16 + rl;
    const int swz = (n ^ (n >> 2) ^ (n >> 4)) & 7;
#pragma unroll
    for (int ks = 0; ks < 2; ++ks)
      bbF[nf][ks] = n * 128 + (((ks * 4 + kg) ^ swz) << 4);
  }

  f32x4 acc[4][4];
#pragma unroll
  for (int mf = 0; mf < 4; ++mf)
#pragma unroll
    for (int nf = 0; nf < 4; ++nf) acc[mf][nf] = (f32x4)(0.0f);

  const bool mact = (wm * 64) < ne;

  auto compute = [&](const char* Ab, const char* Bb) {
#pragma unroll
    for (int ks = 0; ks < 2; ++ks) {
      bf16x8 bfr[4];
#pragma unroll
      for (int nf = 0; nf < 4; ++nf)
        bfr[nf] = *reinterpret_cast<const bf16x8*>(Bb + bbF[nf][ks]);
#pragma unroll
      for (int mf = 0; mf < 4; ++mf) {
        bf16x8 af = *reinterpret_cast<const bf16x8*>(Ab + abyte[ks] + mf * 2048);
#pragma unroll
        for (int nf = 0; nf < 4; ++nf)
          acc[mf][nf] = __builtin_amdgcn_mfma_f32_16x16x32_bf16(af, bfr[nf], acc[mf][nf], 0, 0, 0);
      }
    }
  };

  f32x4 a0, a1, b0, b1;  // two named B half-sets (rule #20)

#define LGKM0 asm volatile("s_waitcnt lgkmcnt(0)" ::: "memory")
#define VMW(N) asm volatile("s_waitcnt vmcnt(" #N ")" ::: "memory")
#define BARRIER asm volatile("s_barrier" ::: "memory")
  // step T: entry in flight = {bhA(T+1):2, bhB(T+1):2, A(T+1):2}
#define FSTEP(T, AB, BSR, BSW)                 \
  {                                            \
    if (mact) compute(AB, BSR);                \
    VMW(4);  /* bhA(T+1) data in a regs */     \
    writeH(BSW, 0, a0, a1);                    \
    loadH((T) + 2, 0, a0, a1);                 \
    VMW(4);  /* bhB(T+1) data in b regs */     \
    writeH(BSW, 1, b0, b1);                    \
    loadH((T) + 2, 1, b0, b1);                 \
    LGKM0;                                     \
    VMW(4);  /* A(T+1) landed in LDS */        \
    BARRIER;                                   \
    stageA((T) + 2, AB);                       \
  }

  // ---- prologue ----
  loadH(0, 0, a0, a1);
  loadH(0, 1, b0, b1);
  stageA(0, Ab0);
  VMW(4);  writeH(Bs0, 0, a0, a1);  loadH(1, 0, a0, a1);
  VMW(4);  writeH(Bs0, 1, b0, b1);  loadH(1, 1, b0, b1);
  LGKM0;
  VMW(4);  // A(0) landed; {bhA(1), bhB(1), A(1)} remain
  BARRIER;
  stageA(1, Ab1);

  // ---- main loop: T = 0..NK-3, unrolled x2 for A/B LDS parity ----
  for (int t2 = 0; t2 < NK - 2; t2 += 2) {
    FSTEP(t2,     Ab0, Bs0, Bs1);
    FSTEP(t2 + 1, Ab1, Bs1, Bs0);
  }

  // ---- tail T = NK-2 (even), then NK-1 ----
  if (mact) compute(Ab0, Bs0);
  VMW(4);  writeH(Bs1, 0, a0, a1);
  VMW(2);  writeH(Bs1, 1, b0, b1);
  LGKM0;
  VMW(0);  // A(NK-1) landed
  BARRIER;
  if (mact) compute(Ab1, Bs1);
#undef FSTEP
#undef LGKM0
#undef VMW
#undef BARRIER

  // ---- epilogue ----
  if (mact) {
    const int rg = (lane >> 4) * 4;
    float bc[4];
#pragma unroll
    for (int nf = 0; nf < 4; ++nf)
      bc[nf] = (MODE == 1 && kh != 0) ? 0.0f
             : bias[(long)e * NDIM + n0 + wn * 64 + nf * 16 + rl];
#pragma unroll
    for (int mf = 0; mf < 4; ++mf) {
#pragma unroll
      for (int r = 0; r < 4; ++r) {
        const int row = wm * 64 + mf * 16 + rg + r;
        if (row < ne) {
          const int gid = gidlist[glist0 + row];
#pragma unroll
          for (int nf = 0; nf < 4; ++nf) {
            const int col = n0 + wn * 64 + nf * 16 + rl;
            float v = acc[mf][nf][r] + bc[nf];
            if constexpr (MODE == 0) {
              v = fmaxf(v, 0.0f);
              Hout[(long)gid * NDIM + col] = f2bf(v);
            } else {
              v *= tw[gid];
              atomicAdd(Oout + (long)(gid >> 1) * NDIM + col, v);
            }
          }
        }
      }
    }
  }
}

extern "C" void kernel_launch(void* const* d_in, const int* in_sizes, int n_in,
                              void* d_out, int out_size, void* d_ws, size_t ws_size,
                              hipStream_t stream) {
  const float* tokens = (const float*)d_in[0];
  const int* idx      = (const int*)d_in[1];
  const float* tw     = (const float*)d_in[2];
  const float* w1     = (const float*)d_in[3];
  const float* b1     = (const float*)d_in[4];
  const float* w2     = (const float*)d_in[5];
  const float* b2     = (const float*)d_in[6];
  float* out = (float*)d_out;

  char* ws = (char*)d_ws;
  int* counts  = (int*)ws;
  int* gidlist = (int*)(ws + 1024);
  unsigned short* A1   = (unsigned short*)(ws + 32768);
  unsigned short* hbuf = (unsigned short*)(ws + 32768 + (size_t)NTOK * HID * 2);

  hipMemsetAsync(out, 0, (size_t)NTOK * HID * sizeof(float), stream);
  route_kernel<<<1, 256, 0, stream>>>(idx, counts, gidlist);
  prep_a_kernel<<<(NTOK * HID / 4) / 256, 256, 0, stream>>>(tokens, A1);

  hipFuncSetAttribute((const void*)moe_gemm_kernel<HID, INTER_D, 0, 1>,
                      hipFuncAttributeMaxDynamicSharedMemorySize, 131072);
  hipFuncSetAttribute((const void*)moe_gemm_kernel<INTER_D, HID, 1, 2>,
                      hipFuncAttributeMaxDynamicSharedMemorySize, 131072);

  // G1: 16 experts x 16 n-chunks = 256 blocks
  moe_gemm_kernel<HID, INTER_D, 0, 1><<<E_N * (INTER_D / 256), 1024, 131072, stream>>>(
      A1, w1, b1, nullptr, counts, gidlist, hbuf, nullptr);
  // G2: 16 experts x 8 n-chunks x 2 K-halves = 256 blocks
  moe_gemm_kernel<INTER_D, HID, 1, 2><<<E_N * (HID / 256) * 2, 1024, 131072, stream>>>(
      hbuf, w2, b2, tw, counts, gidlist, nullptr, out);
}

// Round 8
// 294.015 us; speedup vs baseline: 1.7635x; 1.7635x over previous
//
#include <hip/hip_runtime.h>
#include <stdint.h>

#define E_N 16
#define HID 2048
#define INTER_D 4096
#define NPAIR 2048
#define NTOK 1024
#define CAP 256

typedef __attribute__((ext_vector_type(8))) short bf16x8;
typedef __attribute__((ext_vector_type(4))) float f32x4;

static __device__ __forceinline__ unsigned short f2bf(float f) {
  union { float f; unsigned int u; } x; x.f = f;
  unsigned int r = x.u + 0x7fffu + ((x.u >> 16) & 1u);
  return (unsigned short)(r >> 16);
}

// ---------------- routing: per-expert pair lists ----------------
__global__ void route_kernel(const int* __restrict__ idx, int* __restrict__ counts,
                             int* __restrict__ gidlist) {
  __shared__ int cnt[E_N];
  const int tid = threadIdx.x;
  if (tid < E_N) cnt[tid] = 0;
  for (int j = tid; j < E_N * CAP; j += 256) gidlist[j] = 0;  // pad with valid gid 0
  __syncthreads();
  for (int p = tid; p < NPAIR; p += 256) {
    int e = idx[p] & 15;
    int pos = atomicAdd(&cnt[e], 1);
    if (pos < CAP) gidlist[e * CAP + pos] = p;
  }
  __syncthreads();
  if (tid < E_N) counts[tid] = (cnt[tid] < CAP) ? cnt[tid] : CAP;
}

// ---------------- tokens fp32 -> bf16 ----------------
__global__ void prep_a_kernel(const float* __restrict__ tok, unsigned short* __restrict__ A1) {
  const int i = (blockIdx.x * 256 + threadIdx.x) * 4;
  const float4 v = *reinterpret_cast<const float4*>(tok + i);
  ushort4 o;
  o.x = f2bf(v.x); o.y = f2bf(v.y); o.z = f2bf(v.z); o.w = f2bf(v.w);
  *reinterpret_cast<ushort4*>(A1 + i) = o;
}

// ---------------- grouped GEMM: A direct global->VGPR, LDS carries B only ----
// MODE 0: h = bf16(relu(A1 @ w1 + b1))   KDT=2048, NDIM=4096
// MODE 1: out += tw * (h @ w2 + b2)      KDT=4096, NDIM=2048
// BM=256, BN=128, BK=64; 512 threads = 8 waves (4M x 2N), per-wave 64x64.
// LDS = 2 x 16 KiB B tiles only. One raw s_barrier + lgkmcnt(0) per K-step.
// All loads are register-destination -> compiler emits precise counted waitcnts;
// A-frags double-buffered in VGPRs (aA/aB), B global regs double-named (pA/pB).
template <int KDT, int NDIM, int MODE>
__global__ __launch_bounds__(512, 2) void moe_gemm_kernel(
    const unsigned short* __restrict__ Asrc,  // bf16 rows, stride KDT
    const float* __restrict__ W,              // [E][KDT][NDIM] fp32
    const float* __restrict__ bias,           // [E][NDIM]
    const float* __restrict__ tw,             // [NPAIR] (MODE 1)
    const int* __restrict__ counts,
    const int* __restrict__ gidlist,
    unsigned short* __restrict__ Hout,        // MODE 0
    float* __restrict__ Oout) {               // MODE 1 (atomic)
  constexpr int NK = KDT / 64;                // 32 (G1) / 64 (G2)
  const int e = blockIdx.y;
  const int ne = counts[e];
  if (ne <= 0) return;
  const int n0 = blockIdx.x * 128;
  const int tid = threadIdx.x;
  const int lane = tid & 63;
  const int wv = tid >> 6;   // 0..7
  const int wm = wv >> 1;    // M group of 64 rows (0..3)
  const int wn = wv & 1;     // N group of 64 cols (0..1)

  extern __shared__ char smem[];
  char* Bs0 = smem;            // 16 KiB B tile bf16 [128 n][64 k], XOR-swizzled
  char* Bs1 = smem + 16384;
  __shared__ int sgid[CAP];
  if (tid < CAP) sgid[tid] = gidlist[e * CAP + tid];
  __syncthreads();

  const int rl = lane & 15;
  const int kg = lane >> 4;  // 0..3

  // ---- A fragment base pointers (per-lane, direct global; lanes kg*16B tile a
  //      64B line per row -> full line utilization, L2/L3-resident) ----
  const unsigned short* afp[4];
#pragma unroll
  for (int mf = 0; mf < 4; ++mf) {
    const int row = wm * 64 + mf * 16 + rl;
    const int gid = sgid[row];
    const long arow = (MODE == 0) ? (gid >> 1) : gid;
    afp[mf] = Asrc + arow * (long)KDT + kg * 8;
  }

  // ---- B staging: R2's coalesced map, extended to 4 k-rows/thread ----
  // lanes 0-31 cover 512B contiguous n-span per k-row.
  const int n4 = (tid & 31) * 4;
  const int k4 = (tid >> 5) * 4;  // 0..60
  const float* wbase = W + (long)e * KDT * NDIM + n0 + n4;
  int bby[4];
#pragma unroll
  for (int c = 0; c < 4; ++c)
    bby[c] = (((n4 + c) * 128) + k4 * 2) ^ ((tid & 7) << 4);

  auto loadB = [&](int t, f32x4& r0, f32x4& r1, f32x4& r2, f32x4& r3) {
    const float* p = wbase + (long)(t * 64 + k4) * NDIM;
    r0 = *reinterpret_cast<const f32x4*>(p);
    r1 = *reinterpret_cast<const f32x4*>(p + NDIM);
    r2 = *reinterpret_cast<const f32x4*>(p + 2 * NDIM);
    r3 = *reinterpret_cast<const f32x4*>(p + 3 * NDIM);
  };
  auto writeB = [&](char* Bb, const f32x4& r0, const f32x4& r1,
                    const f32x4& r2, const f32x4& r3) {
#pragma unroll
    for (int c = 0; c < 4; ++c) {
      unsigned long long u =
          (unsigned long long)f2bf(r0[c]) |
          ((unsigned long long)f2bf(r1[c]) << 16) |
          ((unsigned long long)f2bf(r2[c]) << 32) |
          ((unsigned long long)f2bf(r3[c]) << 48);
      *reinterpret_cast<unsigned long long*>(Bb + bby[c]) = u;
    }
  };

  // ---- B fragment LDS byte offsets ----
  int bbF[4][2];
#pragma unroll
  for (int nf = 0; nf < 4; ++nf) {
    const int n = wn * 64 + nf * 16 + rl;
#pragma unroll
    for (int ks = 0; ks < 2; ++ks)
      bbF[nf][ks] = (n * 128 + (ks * 32 + kg * 8) * 2) ^ (((n >> 2) & 7) << 4);
  }

  f32x4 acc[4][4];
#pragma unroll
  for (int mf = 0; mf < 4; ++mf)
#pragma unroll
    for (int nf = 0; nf < 4; ++nf) acc[mf][nf] = (f32x4)(0.0f);

  bf16x8 aA[4][2], aB[4][2];  // A-frag double buffer (static indices only)
  auto loadA = [&](int t, bf16x8 dst[4][2]) {
#pragma unroll
    for (int mf = 0; mf < 4; ++mf)
#pragma unroll
      for (int ks = 0; ks < 2; ++ks)
        dst[mf][ks] = *reinterpret_cast<const bf16x8*>(afp[mf] + t * 64 + ks * 32);
  };
  auto compute = [&](const char* Bb, const bf16x8 af[4][2]) {
    bf16x8 bfr[4][2];
#pragma unroll
    for (int nf = 0; nf < 4; ++nf)
#pragma unroll
      for (int ks = 0; ks < 2; ++ks)
        bfr[nf][ks] = *reinterpret_cast<const bf16x8*>(Bb + bbF[nf][ks]);
#pragma unroll
    for (int ks = 0; ks < 2; ++ks)
#pragma unroll
      for (int mf = 0; mf < 4; ++mf)
#pragma unroll
        for (int nf = 0; nf < 4; ++nf)
          acc[mf][nf] = __builtin_amdgcn_mfma_f32_16x16x32_bf16(
              af[mf][ks], bfr[nf][ks], acc[mf][nf], 0, 0, 0);
  };

  const bool mact = (wm * 64) < ne;
  f32x4 pA0, pA1, pA2, pA3, pB0, pB1, pB2, pB3;  // B reg sets (even/odd tiles)

#define LGKM0 asm volatile("s_waitcnt lgkmcnt(0)" ::: "memory")
#define BARRIER asm volatile("s_barrier" ::: "memory")

  if (mact) {
    // prologue: order B(0), B(1), A(0) so issue order matches steady state
    loadB(0, pA0, pA1, pA2, pA3);
    loadB(1, pB0, pB1, pB2, pB3);
    loadA(0, aA);
    writeB(Bs0, pA0, pA1, pA2, pA3);  // compiler waits B(0) regs
    LGKM0; BARRIER;
    for (int t2 = 0; t2 < NK - 2; t2 += 2) {
      // t even: publish B(t+1)->Bs1, compute(Bs0, aA)
      loadB(t2 + 2, pA0, pA1, pA2, pA3);
      loadA(t2 + 1, aB);
      writeB(Bs1, pB0, pB1, pB2, pB3);
      compute(Bs0, aA);
      LGKM0; BARRIER;
      // t odd
      loadB(t2 + 3, pB0, pB1, pB2, pB3);
      loadA(t2 + 2, aA);
      writeB(Bs0, pA0, pA1, pA2, pA3);
      compute(Bs1, aB);
      LGKM0; BARRIER;
    }
    // t = NK-2 (even): last A prefetch, publish B(NK-1)
    loadA(NK - 1, aB);
    writeB(Bs1, pB0, pB1, pB2, pB3);
    compute(Bs0, aA);
    LGKM0; BARRIER;
    // t = NK-1
    compute(Bs1, aB);
  } else {
    // stage-only path: identical barrier count (NK), no A loads / MFMA
    loadB(0, pA0, pA1, pA2, pA3);
    loadB(1, pB0, pB1, pB2, pB3);
    writeB(Bs0, pA0, pA1, pA2, pA3);
    LGKM0; BARRIER;
    for (int t2 = 0; t2 < NK - 2; t2 += 2) {
      loadB(t2 + 2, pA0, pA1, pA2, pA3);
      writeB(Bs1, pB0, pB1, pB2, pB3);
      LGKM0; BARRIER;
      loadB(t2 + 3, pB0, pB1, pB2, pB3);
      writeB(Bs0, pA0, pA1, pA2, pA3);
      LGKM0; BARRIER;
    }
    writeB(Bs1, pB0, pB1, pB2, pB3);
    LGKM0; BARRIER;
  }
#undef LGKM0
#undef BARRIER

  // ---- epilogue ----
  if (mact) {
    const int rg = (lane >> 4) * 4;
    float bc[4];
#pragma unroll
    for (int nf = 0; nf < 4; ++nf)
      bc[nf] = bias[(long)e * NDIM + n0 + wn * 64 + nf * 16 + rl];
#pragma unroll
    for (int mf = 0; mf < 4; ++mf) {
#pragma unroll
      for (int r = 0; r < 4; ++r) {
        const int row = wm * 64 + mf * 16 + rg + r;
        if (row < ne) {
          const int gid = sgid[row];
#pragma unroll
          for (int nf = 0; nf < 4; ++nf) {
            const int col = n0 + wn * 64 + nf * 16 + rl;
            float v = acc[mf][nf][r] + bc[nf];
            if constexpr (MODE == 0) {
              v = fmaxf(v, 0.0f);
              Hout[(long)gid * NDIM + col] = f2bf(v);
            } else {
              v *= tw[gid];
              atomicAdd(Oout + (long)(gid >> 1) * NDIM + col, v);
            }
          }
        }
      }
    }
  }
}

extern "C" void kernel_launch(void* const* d_in, const int* in_sizes, int n_in,
                              void* d_out, int out_size, void* d_ws, size_t ws_size,
                              hipStream_t stream) {
  const float* tokens = (const float*)d_in[0];
  const int* idx      = (const int*)d_in[1];
  const float* tw     = (const float*)d_in[2];
  const float* w1     = (const float*)d_in[3];
  const float* b1     = (const float*)d_in[4];
  const float* w2     = (const float*)d_in[5];
  const float* b2     = (const float*)d_in[6];
  float* out = (float*)d_out;

  char* ws = (char*)d_ws;
  int* counts  = (int*)ws;
  int* gidlist = (int*)(ws + 1024);
  unsigned short* A1   = (unsigned short*)(ws + 32768);
  unsigned short* hbuf = (unsigned short*)(ws + 32768 + (size_t)NTOK * HID * 2);

  hipMemsetAsync(out, 0, (size_t)NTOK * HID * sizeof(float), stream);
  route_kernel<<<1, 256, 0, stream>>>(idx, counts, gidlist);
  prep_a_kernel<<<(NTOK * HID / 4) / 256, 256, 0, stream>>>(tokens, A1);

  dim3 g1(INTER_D / 128, E_N);  // 32 x 16 = 512 blocks
  moe_gemm_kernel<HID, INTER_D, 0><<<g1, 512, 32768, stream>>>(
      A1, w1, b1, nullptr, counts, gidlist, hbuf, nullptr);
  dim3 g2(HID / 128, E_N);      // 16 x 16 = 256 blocks
  moe_gemm_kernel<INTER_D, HID, 1><<<g2, 512, 32768, stream>>>(
      hbuf, w2, b2, tw, counts, gidlist, nullptr, out);
}